// Round 1
// 11085.129 us; speedup vs baseline: 1.6932x; 1.6932x over previous
//
#include <hip/hip_runtime.h>
#include <cmath>

// ViT backbone. GEMMs via bf16x6 (triple-split) error-compensated MFMA (16x16x32),
// per-product error ~2^-25 (better than fp32 per-op rounding) so top-k order is
// preserved vs the fp32 reference. Rest fp32.
// D=768, H=12, DH=64, NL=12, B=32, L=197 (main) / 101 (last block), k=100.
//
// R1: attention rewritten as one block per (b,h): K/V staged once in LDS
// (K transposed for contiguous ds_read_b128), register-tiled scores/PV,
// XOR-swizzled transposed score buffer. Replaces the latency-bound 9600-block
// scalar attn_k (931us/dispatch, VALUBusy 14.5%, HBM 2.6%).

#define NHEAD 12

typedef __attribute__((ext_vector_type(8))) short short8;
typedef __attribute__((ext_vector_type(4))) float f32x4;

// ---- RN bf16 with exact residual ----
__device__ __forceinline__ short rnb(float x, float& rem) {
    unsigned u = __float_as_uint(x);
    unsigned hr = (u + 0x7FFFu + ((u >> 16) & 1u)) >> 16;
    rem = x - __uint_as_float(hr << 16);
    return (short)hr;
}
// x = h + m + l (all bf16), dropped error ~2^-27 |x|
__device__ __forceinline__ void split3(float x, short& h, short& m, short& l) {
    float r1, r2, r3;
    h = rnb(x, r1);
    m = rnb(r1, r2);
    l = rnb(r2, r3);
}

__device__ __forceinline__ void ldg2lds(const void* g, void* l) {
    __builtin_amdgcn_global_load_lds((const __attribute__((address_space(1))) void*)g,
                                     (__attribute__((address_space(3))) void*)l, 16, 0, 0);
}

// ---------------- MFMA GEMM: C(MxN) = A(MxK) @ Bt(NxK)^T + bias [+R] [gelu] ----------------
// A as bf16 triple (Ah,Am,Al) row-major [M][K]; B as bf16 triple [N][K] (pre-transposed).
// OP 0: C = acc + bias                 (fp32 out)
// OP 1: C = acc + bias + R             (fp32 out, residual)
// OP 2: C* = split3(gelu(acc+bias))    (bf16-triple out)
template<int OP>
__global__ __launch_bounds__(256, 2) void mgemm_k(
    const short* __restrict__ Ah, const short* __restrict__ Am, const short* __restrict__ Al,
    const short* __restrict__ Bh, const short* __restrict__ Bm, const short* __restrict__ Bl,
    const float* __restrict__ bias, const float* __restrict__ R,
    float* __restrict__ C, short* __restrict__ Ch, short* __restrict__ Cm, short* __restrict__ Cl,
    int M, int N, int K, int ldc)
{
    __shared__ short sA[3][128 * 32];
    __shared__ short sB[3][128 * 32];
    const int tid = threadIdx.x;
    const int wid = tid >> 6, lane = tid & 63;
    const int wm = wid >> 1, wn = wid & 1;
    const int quad = lane >> 4, l15 = lane & 15;
    const int row0 = blockIdx.y * 128, col0 = blockIdx.x * 128;

    f32x4 acc[4][4];
#pragma unroll
    for (int i = 0; i < 4; ++i)
#pragma unroll
        for (int j = 0; j < 4; ++j) { acc[i][j][0] = 0.f; acc[i][j][1] = 0.f; acc[i][j][2] = 0.f; acc[i][j][3] = 0.f; }

    const int srow = lane >> 2;          // 0..15
    const int schunk = (lane & 3) * 8;   // k-element offset of this lane's 16B

    for (int k0 = 0; k0 < K; k0 += 32) {
#pragma unroll
        for (int rnd = 0; rnd < 2; ++rnd) {
            int m = rnd * 64 + wid * 16 + srow;            // row within tile, 0..127
            int gr = row0 + m; if (gr > M - 1) gr = M - 1; // clamp (stores masked later)
            int gn = col0 + m;                             // N always multiple of 128
            size_t ao = (size_t)gr * K + k0 + schunk;
            size_t bo = (size_t)gn * K + k0 + schunk;
            int lofs = (rnd * 64 + wid * 16) * 32;
            ldg2lds(Ah + ao, &sA[0][lofs]);
            ldg2lds(Am + ao, &sA[1][lofs]);
            ldg2lds(Al + ao, &sA[2][lofs]);
            ldg2lds(Bh + bo, &sB[0][lofs]);
            ldg2lds(Bm + bo, &sB[1][lofs]);
            ldg2lds(Bl + bo, &sB[2][lofs]);
        }
        __syncthreads();

        short8 a[4][3];
#pragma unroll
        for (int i = 0; i < 4; ++i) {
            int m = wm * 64 + i * 16 + l15;
#pragma unroll
            for (int p = 0; p < 3; ++p)
                a[i][p] = *(const short8*)&sA[p][m * 32 + quad * 8];
        }
#pragma unroll
        for (int j = 0; j < 4; ++j) {
            int n = wn * 64 + j * 16 + l15;
            short8 bh = *(const short8*)&sB[0][n * 32 + quad * 8];
            short8 bm = *(const short8*)&sB[1][n * 32 + quad * 8];
            short8 bl = *(const short8*)&sB[2][n * 32 + quad * 8];
#pragma unroll
            for (int i = 0; i < 4; ++i) {
                // small terms first, then large (chained fp32 accumulate)
                acc[i][j] = __builtin_amdgcn_mfma_f32_16x16x32_bf16(a[i][2], bh, acc[i][j], 0, 0, 0); // l*h
                acc[i][j] = __builtin_amdgcn_mfma_f32_16x16x32_bf16(a[i][0], bl, acc[i][j], 0, 0, 0); // h*l
                acc[i][j] = __builtin_amdgcn_mfma_f32_16x16x32_bf16(a[i][1], bm, acc[i][j], 0, 0, 0); // m*m
                acc[i][j] = __builtin_amdgcn_mfma_f32_16x16x32_bf16(a[i][1], bh, acc[i][j], 0, 0, 0); // m*h
                acc[i][j] = __builtin_amdgcn_mfma_f32_16x16x32_bf16(a[i][0], bm, acc[i][j], 0, 0, 0); // h*m
                acc[i][j] = __builtin_amdgcn_mfma_f32_16x16x32_bf16(a[i][0], bh, acc[i][j], 0, 0, 0); // h*h
            }
        }
        __syncthreads();
    }

#pragma unroll
    for (int i = 0; i < 4; ++i) {
#pragma unroll
        for (int r = 0; r < 4; ++r) {
            int gr = row0 + wm * 64 + i * 16 + quad * 4 + r;
            if (gr >= M) continue;
#pragma unroll
            for (int j = 0; j < 4; ++j) {
                int gc = col0 + wn * 64 + j * 16 + l15;
                float v = acc[i][j][r] + bias[gc];
                if (OP == 1) v += R[(size_t)gr * ldc + gc];
                if (OP == 2) {
                    v = 0.5f * v * (1.f + erff(v * 0.70710678118654752f));
                    short h, m, l; split3(v, h, m, l);
                    size_t o = (size_t)gr * ldc + gc;
                    Ch[o] = h; Cm[o] = m; Cl[o] = l;
                } else {
                    C[(size_t)gr * ldc + gc] = v;
                }
            }
        }
    }
}

// ---------------- weight transpose + split: W[K][N] (ld) -> triple [N][K] ----------------
__global__ __launch_bounds__(256) void ts_k(
    const float* __restrict__ W, int ld,
    short* __restrict__ Bh, short* __restrict__ Bm, short* __restrict__ Bl, int K, int N)
{
    __shared__ float tile[32][33];
    int n0 = blockIdx.x * 32, k0 = blockIdx.y * 32;
    int c = threadIdx.x & 31, r0 = threadIdx.x >> 5;
    for (int rr = r0; rr < 32; rr += 8)
        tile[rr][c] = W[(size_t)(k0 + rr) * ld + n0 + c];
    __syncthreads();
    for (int rr = r0; rr < 32; rr += 8) {
        float v = tile[c][rr];  // = W[k0+c][n0+rr]
        short h, m, l; split3(v, h, m, l);
        size_t o = (size_t)(n0 + rr) * K + k0 + c;
        Bh[o] = h; Bm[o] = m; Bl[o] = l;
    }
}

// ---------------- elementwise split (conv_w already [n][k]; also T -> triple) ----------------
__global__ __launch_bounds__(256) void esplit_k(
    const float* __restrict__ X, short* __restrict__ H, short* __restrict__ Mm,
    short* __restrict__ Lo, int n)
{
    int i = blockIdx.x * 256 + threadIdx.x;
    if (i < n) { short h, m, l; split3(X[i], h, m, l); H[i] = h; Mm[i] = m; Lo[i] = l; }
}

// ---------------- LayerNorm row=768; MODE0: fp32 out, MODE1: bf16-triple out ----------------
template<int MODE>
__global__ __launch_bounds__(256) void ln_k(
    const float* __restrict__ x, const float* __restrict__ s,
    const float* __restrict__ bb, float* __restrict__ y,
    short* __restrict__ yh, short* __restrict__ ym, short* __restrict__ yl)
{
    int r = blockIdx.x;
    int tid = threadIdx.x;
    const float* xr = x + (size_t)r * 768;
    float v0 = xr[tid], v1 = xr[tid + 256], v2 = xr[tid + 512];
    __shared__ float red[256];
    red[tid] = v0 + v1 + v2;
    __syncthreads();
    for (int off = 128; off > 0; off >>= 1) {
        if (tid < off) red[tid] += red[tid + off];
        __syncthreads();
    }
    float m = red[0] / 768.f;
    __syncthreads();
    float d0 = v0 - m, d1 = v1 - m, d2 = v2 - m;
    red[tid] = d0 * d0 + d1 * d1 + d2 * d2;
    __syncthreads();
    for (int off = 128; off > 0; off >>= 1) {
        if (tid < off) red[tid] += red[tid + off];
        __syncthreads();
    }
    float inv = 1.f / sqrtf(red[0] / 768.f + 1e-6f);
    float o0 = d0 * inv * s[tid] + bb[tid];
    float o1 = d1 * inv * s[tid + 256] + bb[tid + 256];
    float o2 = d2 * inv * s[tid + 512] + bb[tid + 512];
    if (MODE == 0) {
        float* yr = y + (size_t)r * 768;
        yr[tid] = o0; yr[tid + 256] = o1; yr[tid + 512] = o2;
    } else {
        size_t base = (size_t)r * 768;
        short h, mm2, l;
        split3(o0, h, mm2, l); yh[base + tid] = h;       ym[base + tid] = mm2;       yl[base + tid] = l;
        split3(o1, h, mm2, l); yh[base + tid + 256] = h; ym[base + tid + 256] = mm2; yl[base + tid + 256] = l;
        split3(o2, h, mm2, l); yh[base + tid + 512] = h; ym[base + tid + 512] = mm2; yl[base + tid + 512] = l;
    }
}

// ---------------- fused attention v2: one block per (b,h) ----------------
// K staged transposed in LDS (sKt[d][k2], contiguous b128 reads along k2),
// V staged natural (sV[k2][d]) via global_load_lds. q swept in 32-row tiles:
//   scores: thread tile 4q x 8k2, FMA-bound;  softmax: 8 segs x 32 qcols;
//   PV: 4-k2 blocked, thread tile 4q x 2d; 1/sum applied in epilogue.
// ps stored transposed [k2][q] with XOR chunk swizzle (chunk ^= k2>>3) to
// break the stride-144B bank conflict. Padded k2 rows get -1e30 -> exp()=0,
// so no LDS zero-fill is needed anywhere.
#define FMA8(qj, ka, kb, ac) \
    ac[0] = fmaf(qj, ka.x, ac[0]); ac[1] = fmaf(qj, ka.y, ac[1]); \
    ac[2] = fmaf(qj, ka.z, ac[2]); ac[3] = fmaf(qj, ka.w, ac[3]); \
    ac[4] = fmaf(qj, kb.x, ac[4]); ac[5] = fmaf(qj, kb.y, ac[5]); \
    ac[6] = fmaf(qj, kb.z, ac[6]); ac[7] = fmaf(qj, kb.w, ac[7]);

__global__ __launch_bounds__(256) void attn2_k(
    const float* __restrict__ qkv,
    short* __restrict__ oh, short* __restrict__ om, short* __restrict__ ol, int L)
{
    __shared__ __align__(16) float sKt[64 * 256];   // [d][k2]   64 KB
    __shared__ __align__(16) float sV[208 * 64];    // [k2][d]   52 KB
    __shared__ __align__(16) float qs[32 * 64];     // [q][d]     8 KB
    __shared__ __align__(16) float ps[224 * 36];    // [k2][qswz] 31.5 KB
    __shared__ float red[8 * 32];
    __shared__ float sinv[32];

    const int tid = threadIdx.x;
    const int h = blockIdx.x, b = blockIdx.y;
    const float* base = qkv + (size_t)b * L * 2304;
    const float* qbase = base + h * 64;
    const float* kbase = base + 768 + h * 64;
    const float* vbase = base + 1536 + h * 64;

    // ---- stage K transposed (one-time; write conflicts acceptable) ----
    for (int idx = tid; idx < L * 16; idx += 256) {
        int r = idx >> 4, c = (idx & 15) << 2;
        float4 kv = *(const float4*)(kbase + (size_t)r * 2304 + c);
        sKt[(c + 0) * 256 + r] = kv.x;
        sKt[(c + 1) * 256 + r] = kv.y;
        sKt[(c + 2) * 256 + r] = kv.z;
        sKt[(c + 3) * 256 + r] = kv.w;
    }
    // ---- stage V natural via global_load_lds (row-clamped, dest linear) ----
    {
        int vIters = (L * 16 + 255) >> 8;
        for (int p2 = 0; p2 < vIters; ++p2) {
            int idx = p2 * 256 + tid;
            int r = idx >> 4; if (r > L - 1) r = L - 1;
            ldg2lds(vbase + (size_t)r * 2304 + ((idx & 15) << 2), &sV[idx * 4]);
        }
    }

    const int ko = tid & 31, qq8 = tid >> 5;   // scores: k2-oct, q-quad group
    const int qsm = tid & 31, seg = tid >> 5;  // softmax: q col, k2 segment
    const int pq = tid & 7, dd = tid >> 3;     // PV: q-quad, d-pair
    const int ntiles = (L + 31) >> 5;
    const int Lr4 = (L + 3) & ~3;

    for (int t = 0; t < ntiles; ++t) {
        int q0 = t << 5;
        __syncthreads();   // staging done / prev tile's PV done with ps+qs
        {
            int idx = tid;
            int r = q0 + (idx >> 4); if (r > L - 1) r = L - 1;
            ldg2lds(qbase + (size_t)r * 2304 + ((idx & 15) << 2), &qs[idx * 4]);
            idx = 256 + tid;
            r = q0 + (idx >> 4); if (r > L - 1) r = L - 1;
            ldg2lds(qbase + (size_t)r * 2304 + ((idx & 15) << 2), &qs[idx * 4]);
        }
        __syncthreads();   // qs ready (barrier drains vmcnt)

        // ---- scores: acc[4 q][8 k2] over d=64 ----
        float acc[4][8];
#pragma unroll
        for (int j = 0; j < 4; ++j)
#pragma unroll
            for (int c = 0; c < 8; ++c) acc[j][c] = 0.f;

        const float* kp = &sKt[ko * 8];
#pragma unroll 4
        for (int d4 = 0; d4 < 16; ++d4) {
            float4 k0[4], k1[4];
#pragma unroll
            for (int dd2 = 0; dd2 < 4; ++dd2) {
                int d = d4 * 4 + dd2;
                k0[dd2] = *(const float4*)&kp[d * 256];
                k1[dd2] = *(const float4*)&kp[d * 256 + 4];
            }
#pragma unroll
            for (int j = 0; j < 4; ++j) {
                float4 qv = *(const float4*)&qs[(qq8 * 4 + j) * 64 + d4 * 4];
                FMA8(qv.x, k0[0], k1[0], acc[j]);
                FMA8(qv.y, k0[1], k1[1], acc[j]);
                FMA8(qv.z, k0[2], k1[2], acc[j]);
                FMA8(qv.w, k0[3], k1[3], acc[j]);
            }
        }
        // write ps transposed+swizzled; scale 1/8; mask pad k2 with -1e30
        {
            int chnk = ((qq8 ^ ko) & 7) << 2;
#pragma unroll
            for (int c = 0; c < 8; ++c) {
                int k2 = ko * 8 + c;
                if (k2 < 224) {
                    float4 w;
                    if (k2 < L) {
                        w.x = acc[0][c] * 0.125f; w.y = acc[1][c] * 0.125f;
                        w.z = acc[2][c] * 0.125f; w.w = acc[3][c] * 0.125f;
                    } else { w.x = -1e30f; w.y = -1e30f; w.z = -1e30f; w.w = -1e30f; }
                    *(float4*)&ps[k2 * 36 + chnk] = w;
                }
            }
        }
        __syncthreads();

        // ---- softmax over k2 per q column ----
        float mloc = -1e30f;
#pragma unroll 4
        for (int j2 = 0; j2 < 28; ++j2) {
            int k2 = seg * 28 + j2;
            mloc = fmaxf(mloc, ps[k2 * 36 + ((((qsm >> 2) ^ (k2 >> 3)) & 7) << 2) + (qsm & 3)]);
        }
        red[seg * 32 + qsm] = mloc;
        __syncthreads();
        float mm = red[qsm];
#pragma unroll
        for (int s2 = 1; s2 < 8; ++s2) mm = fmaxf(mm, red[s2 * 32 + qsm]);
        __syncthreads();   // all max-reads done before red is reused for sums
        float sum = 0.f;
#pragma unroll 4
        for (int j2 = 0; j2 < 28; ++j2) {
            int k2 = seg * 28 + j2;
            int o2 = k2 * 36 + ((((qsm >> 2) ^ (k2 >> 3)) & 7) << 2) + (qsm & 3);
            float e = expf(ps[o2] - mm);
            ps[o2] = e;
            sum += e;
        }
        red[seg * 32 + qsm] = sum;
        __syncthreads();
        float tot = red[qsm];
#pragma unroll
        for (int s2 = 1; s2 < 8; ++s2) tot += red[s2 * 32 + qsm];
        if (tid < 32) sinv[tid] = 1.f / tot;
        __syncthreads();

        // ---- PV: acc[4 q][2 d], 4-k2 reduction blocking ----
        float pacc[4][2];
#pragma unroll
        for (int j = 0; j < 4; ++j) { pacc[j][0] = 0.f; pacc[j][1] = 0.f; }
        for (int k2 = 0; k2 < Lr4; k2 += 4) {
#pragma unroll
            for (int i2 = 0; i2 < 4; ++i2) {
                int kk = k2 + i2;
                const float4 pv = *(const float4*)&ps[kk * 36 + (((pq ^ (kk >> 3)) & 7) << 2)];
                const float2 vv = *(const float2*)&sV[kk * 64 + dd * 2];
                pacc[0][0] = fmaf(pv.x, vv.x, pacc[0][0]);
                pacc[0][1] = fmaf(pv.x, vv.y, pacc[0][1]);
                pacc[1][0] = fmaf(pv.y, vv.x, pacc[1][0]);
                pacc[1][1] = fmaf(pv.y, vv.y, pacc[1][1]);
                pacc[2][0] = fmaf(pv.z, vv.x, pacc[2][0]);
                pacc[2][1] = fmaf(pv.z, vv.y, pacc[2][1]);
                pacc[3][0] = fmaf(pv.w, vv.x, pacc[3][0]);
                pacc[3][1] = fmaf(pv.w, vv.y, pacc[3][1]);
            }
        }
#pragma unroll
        for (int j = 0; j < 4; ++j) {
            int grow = q0 + pq * 4 + j;
            if (grow >= L) continue;
            float inv = sinv[pq * 4 + j];
            size_t o = ((size_t)(b * L + grow)) * 768 + h * 64 + dd * 2;
            short hh, mm2, ll;
            split3(pacc[j][0] * inv, hh, mm2, ll);
            oh[o] = hh; om[o] = mm2; ol[o] = ll;
            split3(pacc[j][1] * inv, hh, mm2, ll);
            oh[o + 1] = hh; om[o + 1] = mm2; ol[o + 1] = ll;
        }
    }
}

// ---------------- patch embed helpers ----------------
__global__ __launch_bounds__(256) void gather_k(
    const float* __restrict__ x,
    short* __restrict__ ph, short* __restrict__ pm, short* __restrict__ pl)
{
    int n = blockIdx.x, b = blockIdx.y, tid = threadIdx.x;
    int hp = n / 14, wp = n % 14;
    size_t base = ((size_t)(b * 196 + n)) * 768;
    for (int e = tid; e < 768; e += 256) {
        int c = e >> 8, rem = e & 255, rr = rem >> 4, cc = rem & 15;
        float v = x[((size_t)(b * 3 + c) * 224 + (hp * 16 + rr)) * 224 + wp * 16 + cc];
        short h, m, l; split3(v, h, m, l);
        ph[base + e] = h; pm[base + e] = m; pl[base + e] = l;
    }
}

__global__ __launch_bounds__(256) void embed_k(
    const float* __restrict__ tpatch, const float* __restrict__ cls,
    const float* __restrict__ pos, float* __restrict__ t)
{
    int m = blockIdx.x, b = blockIdx.y, tid = threadIdx.x;
    float* dst = t + ((size_t)(b * 197 + m)) * 768;
    if (m == 0) {
        for (int e = tid; e < 768; e += 256) dst[e] = cls[e] + pos[e];
    } else {
        const float* s2 = tpatch + ((size_t)(b * 196 + m - 1)) * 768;
        for (int e = tid; e < 768; e += 256) dst[e] = s2[e] + pos[(size_t)m * 768 + e];
    }
}

// ---------------- A_hat path (layer-10 attention on RAW t, q-row 0 only) ----------------
__global__ __launch_bounds__(256) void q0_k(
    const float* __restrict__ T, const float* __restrict__ W,
    const float* __restrict__ bq, float* __restrict__ q0)
{
    int b = blockIdx.x, tid = threadIdx.x;
    __shared__ float ys[768];
    const float* yr = T + (size_t)b * 197 * 768;
    ys[tid] = yr[tid]; ys[tid + 256] = yr[tid + 256]; ys[tid + 512] = yr[tid + 512];
    __syncthreads();
    for (int d = tid; d < 768; d += 256) {
        float acc = bq[d];
        for (int k2 = 0; k2 < 768; ++k2) acc += ys[k2] * W[(size_t)k2 * 2304 + d];
        q0[(size_t)b * 768 + d] = acc;
    }
}

__global__ __launch_bounds__(256) void ahat_k(
    const float* __restrict__ kmat, const float* __restrict__ q0,
    float* __restrict__ Ahat)
{
    int b = blockIdx.x, tid = threadIdx.x;
    __shared__ float qs[64];
    __shared__ float sc[256];
    __shared__ float red[256];
    __shared__ float ah[196];
    for (int j = tid; j < 196; j += 256) ah[j] = 0.f;
    for (int h = 0; h < NHEAD; ++h) {
        __syncthreads();
        if (tid < 64) qs[tid] = q0[(size_t)b * 768 + h * 64 + tid];
        __syncthreads();
        if (tid < 197) {
            const float* kr = kmat + ((size_t)(b * 197 + tid)) * 768 + h * 64;
            float acc = 0.f;
            for (int d = 0; d < 64; ++d) acc += qs[d] * kr[d];
            sc[tid] = acc * 0.125f;
        }
        __syncthreads();
        red[tid] = (tid < 197) ? sc[tid] : -1e30f;
        __syncthreads();
        for (int off = 128; off > 0; off >>= 1) {
            if (tid < off) red[tid] = fmaxf(red[tid], red[tid + off]);
            __syncthreads();
        }
        float m = red[0];
        __syncthreads();
        float e = 0.f;
        if (tid < 197) { e = expf(sc[tid] - m); sc[tid] = e; }
        red[tid] = e;
        __syncthreads();
        for (int off = 128; off > 0; off >>= 1) {
            if (tid < off) red[tid] += red[tid + off];
            __syncthreads();
        }
        float inv = 1.f / red[0];
        if (tid >= 1 && tid < 197) ah[tid - 1] += sc[tid] * inv;
    }
    __syncthreads();
    for (int j = tid; j < 196; j += 256) Ahat[(size_t)b * 196 + j] = ah[j];
}

__global__ __launch_bounds__(256) void zo_k(
    const float* __restrict__ t, const float* __restrict__ impw,
    const float* __restrict__ impb, const float* __restrict__ Ahat,
    float* __restrict__ O)
{
    int b = blockIdx.x, tid = threadIdx.x;
    __shared__ float w[768];
    w[tid] = impw[tid]; w[tid + 256] = impw[tid + 256]; w[tid + 512] = impw[tid + 512];
    __syncthreads();
    for (int j = tid; j < 196; j += 256) {
        const float* tr = t + ((size_t)(b * 197) + 1 + j) * 768;
        float acc = impb[0];
        for (int d = 0; d < 768; ++d) acc += tr[d] * w[d];
        float z = 1.f / (1.f + expf(-acc));
        float a = Ahat[(size_t)b * 196 + j];
        O[(size_t)b * 196 + j] = a + a * z;
    }
}

// exact jax.lax.top_k semantics: descending, ties -> lower index first
__global__ __launch_bounds__(256) void topk_k(const float* __restrict__ O, int* __restrict__ idx)
{
    int b = blockIdx.x, tid = threadIdx.x;
    __shared__ float s[196];
    if (tid < 196) s[tid] = O[(size_t)b * 196 + tid];
    __syncthreads();
    if (tid < 196) {
        float v = s[tid];
        int rank = 0;
        for (int i = 0; i < 196; ++i) {
            float u = s[i];
            rank += (u > v) || (u == v && i < tid);
        }
        if (rank < 100) idx[b * 100 + rank] = tid;
    }
}

__global__ __launch_bounds__(256) void build_k(
    const float* __restrict__ t, const float* __restrict__ pos,
    const int* __restrict__ idx, float* __restrict__ inp, float* __restrict__ tp)
{
    int m = blockIdx.x, b = blockIdx.y, tid = threadIdx.x;
    float* dst = inp + ((size_t)(b * 101 + m)) * 768;
    if (m == 0) {
        const float* tr = t + (size_t)b * 197 * 768;
        for (int e = tid; e < 768; e += 256) dst[e] = tr[e] + pos[e];
    } else {
        int j = idx[b * 100 + m - 1];
        const float* tr = t + ((size_t)(b * 197) + 1 + j) * 768;
        const float* pr = pos + (size_t)(1 + j) * 768;
        float* tpr = tp + ((size_t)(b * 100) + (m - 1)) * 768;
        for (int e = tid; e < 768; e += 256) {
            float val = tr[e];
            tpr[e] = val;
            dst[e] = val + pr[e];
        }
    }
}

// ---------------- host side ----------------
extern "C" void kernel_launch(void* const* d_in, const int* in_sizes, int n_in,
                              void* d_out, int out_size, void* d_ws, size_t ws_size,
                              hipStream_t stream)
{
    const float* x      = (const float*)d_in[0];
    const float* conv_w = (const float*)d_in[1];
    const float* conv_b = (const float*)d_in[2];
    const float* cls    = (const float*)d_in[3];
    const float* pos    = (const float*)d_in[4];
    const float* ln1_s  = (const float*)d_in[5];
    const float* ln1_b  = (const float*)d_in[6];
    const float* qkv_w  = (const float*)d_in[7];
    const float* qkv_b  = (const float*)d_in[8];
    const float* proj_w = (const float*)d_in[9];
    const float* proj_b = (const float*)d_in[10];
    const float* ln2_s  = (const float*)d_in[11];
    const float* ln2_b  = (const float*)d_in[12];
    const float* mlp_w1 = (const float*)d_in[13];
    const float* mlp_b1 = (const float*)d_in[14];
    const float* mlp_w2 = (const float*)d_in[15];
    const float* mlp_b2 = (const float*)d_in[16];
    const float* fln_s  = (const float*)d_in[17];
    const float* fln_b  = (const float*)d_in[18];
    const float* imp_w  = (const float*)d_in[19];
    const float* imp_b  = (const float*)d_in[20];

    const size_t SZ_T = (size_t)32 * 197 * 768;   // 4,841,472 el
    const size_t SZ_H = (size_t)32 * 197 * 3072;  // 19,365,888 el
    const size_t SZ_W = (size_t)768 * 3072;       // 2,359,296 el

    // byte-cursor workspace layout (phase-aliased big scratch), total ~189 MB
    char* p = (char*)d_ws;
    auto alloc = [&](size_t bytes) { char* r = p; p += (bytes + 255) & ~(size_t)255; return r; };
    float* T   = (float*)alloc(SZ_T * 4);
    float* INP = (float*)alloc((size_t)32 * 101 * 768 * 4);
    float* Q0  = (float*)alloc(24576 * 4);
    float* AH  = (float*)alloc(6272 * 4);
    float* OV  = (float*)alloc(6272 * 4);
    int*   IDX = (int*)alloc(3200 * 4);
    short* Yh  = (short*)alloc(SZ_T * 2);
    short* Ym  = (short*)alloc(SZ_T * 2);
    short* Yl  = (short*)alloc(SZ_T * 2);
    short* Wh  = (short*)alloc(SZ_W * 2);
    short* Wm  = (short*)alloc(SZ_W * 2);
    short* Wl  = (short*)alloc(SZ_W * 2);
    char*  S   = alloc((size_t)116195328);  // max(QKV 58.1MB + OB 29.0MB, H 116.2MB)
    // phase 1 (attn): QKV fp32 + OB triple
    float* QKV = (float*)S;
    short* OBh = (short*)(S + (size_t)58097664);
    short* OBm = OBh + SZ_T;
    short* OBl = OBm + SZ_T;
    // phase 2 (mlp): H triple overlays everything in S
    short* Hh = (short*)S;
    short* Hm = Hh + SZ_H;
    short* Hl = Hm + SZ_H;

    float* out0 = (float*)d_out;                        // (32,101,768)
    float* out1 = out0 + (size_t)32 * 101 * 768;        // top_patches (32,100,768)

    auto cvt = [&](const float* W, int K, int N, int ld) {
        ts_k<<<dim3(N / 32, K / 32), 256, 0, stream>>>(W, ld, Wh, Wm, Wl, K, N);
    };

    // ---- patch embed ----
    esplit_k<<<(768 * 768) / 256, 256, 0, stream>>>(conv_w, Wh, Wm, Wl, 768 * 768); // conv_w already [n][k]
    gather_k<<<dim3(196, 32), 256, 0, stream>>>(x, Yh, Ym, Yl);
    mgemm_k<0><<<dim3(6, 49), 256, 0, stream>>>(Yh, Ym, Yl, Wh, Wm, Wl, conv_b, nullptr,
                                                QKV, nullptr, nullptr, nullptr, 6272, 768, 768, 768);
    embed_k<<<dim3(197, 32), 256, 0, stream>>>(QKV, cls, pos, T);

    auto run_block = [&](float* X, int L, int i) {
        int M = 32 * L;
        int mt = (M + 127) / 128;
        ln_k<1><<<M, 256, 0, stream>>>(X, ln1_s + i * 768, ln1_b + i * 768, nullptr, Yh, Ym, Yl);
        cvt(qkv_w + (size_t)i * 768 * 2304, 768, 2304, 2304);
        mgemm_k<0><<<dim3(18, mt), 256, 0, stream>>>(Yh, Ym, Yl, Wh, Wm, Wl, qkv_b + (size_t)i * 2304,
                                                     nullptr, QKV, nullptr, nullptr, nullptr, M, 2304, 768, 2304);
        attn2_k<<<dim3(NHEAD, 32), 256, 0, stream>>>(QKV, OBh, OBm, OBl, L);
        cvt(proj_w + (size_t)i * 768 * 768, 768, 768, 768);
        mgemm_k<1><<<dim3(6, mt), 256, 0, stream>>>(OBh, OBm, OBl, Wh, Wm, Wl, proj_b + (size_t)i * 768,
                                                    X, X, nullptr, nullptr, nullptr, M, 768, 768, 768);
        ln_k<1><<<M, 256, 0, stream>>>(X, ln2_s + i * 768, ln2_b + i * 768, nullptr, Yh, Ym, Yl);
        cvt(mlp_w1 + (size_t)i * 768 * 3072, 768, 3072, 3072);
        mgemm_k<2><<<dim3(24, mt), 256, 0, stream>>>(Yh, Ym, Yl, Wh, Wm, Wl, mlp_b1 + (size_t)i * 3072,
                                                     nullptr, nullptr, Hh, Hm, Hl, M, 3072, 768, 3072);
        cvt(mlp_w2 + (size_t)i * 3072 * 768, 3072, 768, 768);
        mgemm_k<1><<<dim3(6, mt), 256, 0, stream>>>(Hh, Hm, Hl, Wh, Wm, Wl, mlp_b2 + (size_t)i * 768,
                                                    X, X, nullptr, nullptr, nullptr, M, 768, 3072, 768);
    };

    for (int i = 0; i < 11; ++i) run_block(T, 197, i);

    // ---- A_hat: layer-10 attention weights on RAW t (no LN), q-row 0 only ----
    esplit_k<<<(int)(SZ_T / 256), 256, 0, stream>>>(T, Yh, Ym, Yl, (int)SZ_T);
    cvt(qkv_w + (size_t)10 * 768 * 2304 + 768, 768, 768, 2304);     // K-slice of qkv_w[10]
    mgemm_k<0><<<dim3(6, 50), 256, 0, stream>>>(Yh, Ym, Yl, Wh, Wm, Wl, qkv_b + (size_t)10 * 2304 + 768,
                                                nullptr, QKV, nullptr, nullptr, nullptr, 6304, 768, 768, 768);
    q0_k<<<32, 256, 0, stream>>>(T, qkv_w + (size_t)10 * 768 * 2304, qkv_b + (size_t)10 * 2304, Q0);
    ahat_k<<<32, 256, 0, stream>>>(QKV, Q0, AH);
    zo_k<<<32, 256, 0, stream>>>(T, imp_w, imp_b, AH, OV);
    topk_k<<<32, 256, 0, stream>>>(OV, IDX);
    build_k<<<dim3(101, 32), 256, 0, stream>>>(T, pos, IDX, INP, out1);

    // ---- last block on gathered tokens (L=101, layer 11) ----
    run_block(INP, 101, 11);

    // ---- final LN -> out0 ----
    ln_k<0><<<32 * 101, 256, 0, stream>>>(INP, fln_s, fln_b, out0, nullptr, nullptr, nullptr);

    (void)in_sizes; (void)n_in; (void)out_size; (void)ws_size;
}

// Round 2
// 8329.150 us; speedup vs baseline: 2.2534x; 1.3309x over previous
//
#include <hip/hip_runtime.h>
#include <hip/hip_fp16.h>
#include <cmath>

// ViT backbone. GEMMs via fp16x3 (pair-split) error-compensated MFMA (16x16x32_f16):
// x = h + l (both fp16, RN), products l*H + h*L + h*H accumulated fp32.
// Per-product error ~2^-21 |x||y| (dropped l*L + split residual); fp16 products are
// exact in fp32 accum, so accumulation error == fp32 reference per-op rounding.
// Rest fp32. D=768, H=12, DH=64, NL=12, B=32, L=197 (main) / 101 (last block), k=100.
//
// R1: attention one block per (b,h), K/V LDS-resident, register-tiled.
// R2: bf16x6 -> fp16x3 (halves MFMA count, -33% staging bytes) + double-buffered
//     LDS with next-K-step prefetch issued before compute (T3-minimum 2-phase).

#define NHEAD 12

typedef __attribute__((ext_vector_type(8))) _Float16 half8;
typedef __attribute__((ext_vector_type(4))) float f32x4;

// ---- RN fp16 pair split: x = h + l, dropped error ~2^-22 |x| ----
__device__ __forceinline__ void split2h(float x, short& h, short& l) {
    __half hh = __float2half(x);            // RN
    float r = x - __half2float(hh);         // exact in fp32
    h = __half_as_short(hh);
    l = __half_as_short(__float2half(r));   // RN of residual
}

__device__ __forceinline__ void ldg2lds(const void* g, void* l) {
    __builtin_amdgcn_global_load_lds((const __attribute__((address_space(1))) void*)g,
                                     (__attribute__((address_space(3))) void*)l, 16, 0, 0);
}

// ---------------- MFMA GEMM: C(MxN) = A(MxK) @ Bt(NxK)^T + bias [+R] [gelu] ----------------
// A as fp16 pair (Ah,Al) row-major [M][K]; B as fp16 pair [N][K] (pre-transposed).
// OP 0: C = acc + bias                 (fp32 out)
// OP 1: C = acc + bias + R             (fp32 out, residual)
// OP 2: C* = split2(gelu(acc+bias))    (fp16-pair out)
template<int OP>
__global__ __launch_bounds__(256, 2) void mgemm_k(
    const short* __restrict__ Ah, const short* __restrict__ Al,
    const short* __restrict__ Bh, const short* __restrict__ Bl,
    const float* __restrict__ bias, const float* __restrict__ R,
    float* __restrict__ C, short* __restrict__ Ch, short* __restrict__ Cl,
    int M, int N, int K, int ldc)
{
    __shared__ short sA[2][2][128 * 32];   // [dbuf][h/l][row][k]  32 KB
    __shared__ short sB[2][2][128 * 32];   //                      32 KB
    const int tid = threadIdx.x;
    const int wid = tid >> 6, lane = tid & 63;
    const int wm = wid >> 1, wn = wid & 1;
    const int quad = lane >> 4, l15 = lane & 15;
    const int row0 = blockIdx.y * 128, col0 = blockIdx.x * 128;

    f32x4 acc[4][4];
#pragma unroll
    for (int i = 0; i < 4; ++i)
#pragma unroll
        for (int j = 0; j < 4; ++j) { acc[i][j][0] = 0.f; acc[i][j][1] = 0.f; acc[i][j][2] = 0.f; acc[i][j][3] = 0.f; }

    const int srow = lane >> 2;          // 0..15
    const int schunk = (lane & 3) * 8;   // k-element offset of this lane's 16B
    const int KT = K >> 5;

    auto stage = [&](int buf, int kt) {
        int kk = kt << 5;
#pragma unroll
        for (int rnd = 0; rnd < 2; ++rnd) {
            int m = rnd * 64 + wid * 16 + srow;            // row within tile, 0..127
            int gr = row0 + m; if (gr > M - 1) gr = M - 1; // clamp (stores masked later)
            int gn = col0 + m;                             // N always multiple of 128
            size_t ao = (size_t)gr * K + kk + schunk;
            size_t bo = (size_t)gn * K + kk + schunk;
            int lofs = (rnd * 64 + wid * 16) * 32;         // wave-uniform LDS base
            ldg2lds(Ah + ao, &sA[buf][0][lofs]);
            ldg2lds(Al + ao, &sA[buf][1][lofs]);
            ldg2lds(Bh + bo, &sB[buf][0][lofs]);
            ldg2lds(Bl + bo, &sB[buf][1][lofs]);
        }
    };

    stage(0, 0);
    for (int kt = 0; kt < KT; ++kt) {
        int cur = kt & 1;
        __syncthreads();                    // drains prefetch (covered by prev compute)
        if (kt + 1 < KT) stage(cur ^ 1, kt + 1);

        half8 a[4][2];
#pragma unroll
        for (int i = 0; i < 4; ++i) {
            int m = wm * 64 + i * 16 + l15;
#pragma unroll
            for (int p = 0; p < 2; ++p)
                a[i][p] = *(const half8*)&sA[cur][p][m * 32 + quad * 8];
        }
#pragma unroll
        for (int j = 0; j < 4; ++j) {
            int n = wn * 64 + j * 16 + l15;
            half8 bh = *(const half8*)&sB[cur][0][n * 32 + quad * 8];
            half8 bl = *(const half8*)&sB[cur][1][n * 32 + quad * 8];
#pragma unroll
            for (int i = 0; i < 4; ++i) {
                // small terms first, then large (chained fp32 accumulate)
                acc[i][j] = __builtin_amdgcn_mfma_f32_16x16x32_f16(a[i][1], bh, acc[i][j], 0, 0, 0); // l*H
                acc[i][j] = __builtin_amdgcn_mfma_f32_16x16x32_f16(a[i][0], bl, acc[i][j], 0, 0, 0); // h*L
                acc[i][j] = __builtin_amdgcn_mfma_f32_16x16x32_f16(a[i][0], bh, acc[i][j], 0, 0, 0); // h*H
            }
        }
    }

#pragma unroll
    for (int i = 0; i < 4; ++i) {
#pragma unroll
        for (int r = 0; r < 4; ++r) {
            int gr = row0 + wm * 64 + i * 16 + quad * 4 + r;
            if (gr >= M) continue;
#pragma unroll
            for (int j = 0; j < 4; ++j) {
                int gc = col0 + wn * 64 + j * 16 + l15;
                float v = acc[i][j][r] + bias[gc];
                if (OP == 1) v += R[(size_t)gr * ldc + gc];
                if (OP == 2) {
                    v = 0.5f * v * (1.f + erff(v * 0.70710678118654752f));
                    short h, l; split2h(v, h, l);
                    size_t o = (size_t)gr * ldc + gc;
                    Ch[o] = h; Cl[o] = l;
                } else {
                    C[(size_t)gr * ldc + gc] = v;
                }
            }
        }
    }
}

// ---------------- weight transpose + split: W[K][N] (ld) -> pair [N][K] ----------------
__global__ __launch_bounds__(256) void ts_k(
    const float* __restrict__ W, int ld,
    short* __restrict__ Bh, short* __restrict__ Bl, int K, int N)
{
    __shared__ float tile[32][33];
    int n0 = blockIdx.x * 32, k0 = blockIdx.y * 32;
    int c = threadIdx.x & 31, r0 = threadIdx.x >> 5;
    for (int rr = r0; rr < 32; rr += 8)
        tile[rr][c] = W[(size_t)(k0 + rr) * ld + n0 + c];
    __syncthreads();
    for (int rr = r0; rr < 32; rr += 8) {
        float v = tile[c][rr];  // = W[k0+c][n0+rr]
        short h, l; split2h(v, h, l);
        size_t o = (size_t)(n0 + rr) * K + k0 + c;
        Bh[o] = h; Bl[o] = l;
    }
}

// ---------------- elementwise split (conv_w already [n][k]; also T -> pair) ----------------
__global__ __launch_bounds__(256) void esplit_k(
    const float* __restrict__ X, short* __restrict__ H,
    short* __restrict__ Lo, int n)
{
    int i = blockIdx.x * 256 + threadIdx.x;
    if (i < n) { short h, l; split2h(X[i], h, l); H[i] = h; Lo[i] = l; }
}

// ---------------- LayerNorm row=768; MODE0: fp32 out, MODE1: fp16-pair out ----------------
template<int MODE>
__global__ __launch_bounds__(256) void ln_k(
    const float* __restrict__ x, const float* __restrict__ s,
    const float* __restrict__ bb, float* __restrict__ y,
    short* __restrict__ yh, short* __restrict__ yl)
{
    int r = blockIdx.x;
    int tid = threadIdx.x;
    const float* xr = x + (size_t)r * 768;
    float v0 = xr[tid], v1 = xr[tid + 256], v2 = xr[tid + 512];
    __shared__ float red[256];
    red[tid] = v0 + v1 + v2;
    __syncthreads();
    for (int off = 128; off > 0; off >>= 1) {
        if (tid < off) red[tid] += red[tid + off];
        __syncthreads();
    }
    float m = red[0] / 768.f;
    __syncthreads();
    float d0 = v0 - m, d1 = v1 - m, d2 = v2 - m;
    red[tid] = d0 * d0 + d1 * d1 + d2 * d2;
    __syncthreads();
    for (int off = 128; off > 0; off >>= 1) {
        if (tid < off) red[tid] += red[tid + off];
        __syncthreads();
    }
    float inv = 1.f / sqrtf(red[0] / 768.f + 1e-6f);
    float o0 = d0 * inv * s[tid] + bb[tid];
    float o1 = d1 * inv * s[tid + 256] + bb[tid + 256];
    float o2 = d2 * inv * s[tid + 512] + bb[tid + 512];
    if (MODE == 0) {
        float* yr = y + (size_t)r * 768;
        yr[tid] = o0; yr[tid + 256] = o1; yr[tid + 512] = o2;
    } else {
        size_t base = (size_t)r * 768;
        short h, l;
        split2h(o0, h, l); yh[base + tid] = h;       yl[base + tid] = l;
        split2h(o1, h, l); yh[base + tid + 256] = h; yl[base + tid + 256] = l;
        split2h(o2, h, l); yh[base + tid + 512] = h; yl[base + tid + 512] = l;
    }
}

// ---------------- fused attention v2: one block per (b,h) ----------------
// K staged transposed in LDS (sKt[d][k2], contiguous b128 reads along k2),
// V staged natural (sV[k2][d]) via global_load_lds. q swept in 32-row tiles:
//   scores: thread tile 4q x 8k2, FMA-bound;  softmax: 8 segs x 32 qcols;
//   PV: 4-k2 blocked, thread tile 4q x 2d; 1/sum applied in epilogue.
// ps stored transposed [k2][q] with XOR chunk swizzle (chunk ^= k2>>3) to
// break the stride-144B bank conflict. Padded k2 rows get -1e30 -> exp()=0,
// so no LDS zero-fill is needed anywhere.
#define FMA8(qj, ka, kb, ac) \
    ac[0] = fmaf(qj, ka.x, ac[0]); ac[1] = fmaf(qj, ka.y, ac[1]); \
    ac[2] = fmaf(qj, ka.z, ac[2]); ac[3] = fmaf(qj, ka.w, ac[3]); \
    ac[4] = fmaf(qj, kb.x, ac[4]); ac[5] = fmaf(qj, kb.y, ac[5]); \
    ac[6] = fmaf(qj, kb.z, ac[6]); ac[7] = fmaf(qj, kb.w, ac[7]);

__global__ __launch_bounds__(256) void attn2_k(
    const float* __restrict__ qkv,
    short* __restrict__ oh, short* __restrict__ ol, int L)
{
    __shared__ __align__(16) float sKt[64 * 256];   // [d][k2]   64 KB
    __shared__ __align__(16) float sV[208 * 64];    // [k2][d]   52 KB
    __shared__ __align__(16) float qs[32 * 64];     // [q][d]     8 KB
    __shared__ __align__(16) float ps[224 * 36];    // [k2][qswz] 31.5 KB
    __shared__ float red[8 * 32];
    __shared__ float sinv[32];

    const int tid = threadIdx.x;
    const int h = blockIdx.x, b = blockIdx.y;
    const float* base = qkv + (size_t)b * L * 2304;
    const float* qbase = base + h * 64;
    const float* kbase = base + 768 + h * 64;
    const float* vbase = base + 1536 + h * 64;

    // ---- stage K transposed (one-time; write conflicts acceptable) ----
    for (int idx = tid; idx < L * 16; idx += 256) {
        int r = idx >> 4, c = (idx & 15) << 2;
        float4 kv = *(const float4*)(kbase + (size_t)r * 2304 + c);
        sKt[(c + 0) * 256 + r] = kv.x;
        sKt[(c + 1) * 256 + r] = kv.y;
        sKt[(c + 2) * 256 + r] = kv.z;
        sKt[(c + 3) * 256 + r] = kv.w;
    }
    // ---- stage V natural via global_load_lds (row-clamped, dest linear) ----
    {
        int vIters = (L * 16 + 255) >> 8;
        for (int p2 = 0; p2 < vIters; ++p2) {
            int idx = p2 * 256 + tid;
            int r = idx >> 4; if (r > L - 1) r = L - 1;
            ldg2lds(vbase + (size_t)r * 2304 + ((idx & 15) << 2), &sV[idx * 4]);
        }
    }

    const int ko = tid & 31, qq8 = tid >> 5;   // scores: k2-oct, q-quad group
    const int qsm = tid & 31, seg = tid >> 5;  // softmax: q col, k2 segment
    const int pq = tid & 7, dd = tid >> 3;     // PV: q-quad, d-pair
    const int ntiles = (L + 31) >> 5;
    const int Lr4 = (L + 3) & ~3;

    for (int t = 0; t < ntiles; ++t) {
        int q0 = t << 5;
        __syncthreads();   // staging done / prev tile's PV done with ps+qs
        {
            int idx = tid;
            int r = q0 + (idx >> 4); if (r > L - 1) r = L - 1;
            ldg2lds(qbase + (size_t)r * 2304 + ((idx & 15) << 2), &qs[idx * 4]);
            idx = 256 + tid;
            r = q0 + (idx >> 4); if (r > L - 1) r = L - 1;
            ldg2lds(qbase + (size_t)r * 2304 + ((idx & 15) << 2), &qs[idx * 4]);
        }
        __syncthreads();   // qs ready (barrier drains vmcnt)

        // ---- scores: acc[4 q][8 k2] over d=64 ----
        float acc[4][8];
#pragma unroll
        for (int j = 0; j < 4; ++j)
#pragma unroll
            for (int c = 0; c < 8; ++c) acc[j][c] = 0.f;

        const float* kp = &sKt[ko * 8];
#pragma unroll 4
        for (int d4 = 0; d4 < 16; ++d4) {
            float4 k0[4], k1[4];
#pragma unroll
            for (int dd2 = 0; dd2 < 4; ++dd2) {
                int d = d4 * 4 + dd2;
                k0[dd2] = *(const float4*)&kp[d * 256];
                k1[dd2] = *(const float4*)&kp[d * 256 + 4];
            }
#pragma unroll
            for (int j = 0; j < 4; ++j) {
                float4 qv = *(const float4*)&qs[(qq8 * 4 + j) * 64 + d4 * 4];
                FMA8(qv.x, k0[0], k1[0], acc[j]);
                FMA8(qv.y, k0[1], k1[1], acc[j]);
                FMA8(qv.z, k0[2], k1[2], acc[j]);
                FMA8(qv.w, k0[3], k1[3], acc[j]);
            }
        }
        // write ps transposed+swizzled; scale 1/8; mask pad k2 with -1e30
        {
            int chnk = ((qq8 ^ ko) & 7) << 2;
#pragma unroll
            for (int c = 0; c < 8; ++c) {
                int k2 = ko * 8 + c;
                if (k2 < 224) {
                    float4 w;
                    if (k2 < L) {
                        w.x = acc[0][c] * 0.125f; w.y = acc[1][c] * 0.125f;
                        w.z = acc[2][c] * 0.125f; w.w = acc[3][c] * 0.125f;
                    } else { w.x = -1e30f; w.y = -1e30f; w.z = -1e30f; w.w = -1e30f; }
                    *(float4*)&ps[k2 * 36 + chnk] = w;
                }
            }
        }
        __syncthreads();

        // ---- softmax over k2 per q column ----
        float mloc = -1e30f;
#pragma unroll 4
        for (int j2 = 0; j2 < 28; ++j2) {
            int k2 = seg * 28 + j2;
            mloc = fmaxf(mloc, ps[k2 * 36 + ((((qsm >> 2) ^ (k2 >> 3)) & 7) << 2) + (qsm & 3)]);
        }
        red[seg * 32 + qsm] = mloc;
        __syncthreads();
        float mm = red[qsm];
#pragma unroll
        for (int s2 = 1; s2 < 8; ++s2) mm = fmaxf(mm, red[s2 * 32 + qsm]);
        __syncthreads();   // all max-reads done before red is reused for sums
        float sum = 0.f;
#pragma unroll 4
        for (int j2 = 0; j2 < 28; ++j2) {
            int k2 = seg * 28 + j2;
            int o2 = k2 * 36 + ((((qsm >> 2) ^ (k2 >> 3)) & 7) << 2) + (qsm & 3);
            float e = expf(ps[o2] - mm);
            ps[o2] = e;
            sum += e;
        }
        red[seg * 32 + qsm] = sum;
        __syncthreads();
        float tot = red[qsm];
#pragma unroll
        for (int s2 = 1; s2 < 8; ++s2) tot += red[s2 * 32 + qsm];
        if (tid < 32) sinv[tid] = 1.f / tot;
        __syncthreads();

        // ---- PV: acc[4 q][2 d], 4-k2 reduction blocking ----
        float pacc[4][2];
#pragma unroll
        for (int j = 0; j < 4; ++j) { pacc[j][0] = 0.f; pacc[j][1] = 0.f; }
        for (int k2 = 0; k2 < Lr4; k2 += 4) {
#pragma unroll
            for (int i2 = 0; i2 < 4; ++i2) {
                int kk = k2 + i2;
                const float4 pv = *(const float4*)&ps[kk * 36 + (((pq ^ (kk >> 3)) & 7) << 2)];
                const float2 vv = *(const float2*)&sV[kk * 64 + dd * 2];
                pacc[0][0] = fmaf(pv.x, vv.x, pacc[0][0]);
                pacc[0][1] = fmaf(pv.x, vv.y, pacc[0][1]);
                pacc[1][0] = fmaf(pv.y, vv.x, pacc[1][0]);
                pacc[1][1] = fmaf(pv.y, vv.y, pacc[1][1]);
                pacc[2][0] = fmaf(pv.z, vv.x, pacc[2][0]);
                pacc[2][1] = fmaf(pv.z, vv.y, pacc[2][1]);
                pacc[3][0] = fmaf(pv.w, vv.x, pacc[3][0]);
                pacc[3][1] = fmaf(pv.w, vv.y, pacc[3][1]);
            }
        }
#pragma unroll
        for (int j = 0; j < 4; ++j) {
            int grow = q0 + pq * 4 + j;
            if (grow >= L) continue;
            float inv = sinv[pq * 4 + j];
            size_t o = ((size_t)(b * L + grow)) * 768 + h * 64 + dd * 2;
            short hh, ll;
            split2h(pacc[j][0] * inv, hh, ll);
            oh[o] = hh; ol[o] = ll;
            split2h(pacc[j][1] * inv, hh, ll);
            oh[o + 1] = hh; ol[o + 1] = ll;
        }
    }
}

// ---------------- patch embed helpers ----------------
__global__ __launch_bounds__(256) void gather_k(
    const float* __restrict__ x,
    short* __restrict__ ph, short* __restrict__ pl)
{
    int n = blockIdx.x, b = blockIdx.y, tid = threadIdx.x;
    int hp = n / 14, wp = n % 14;
    size_t base = ((size_t)(b * 196 + n)) * 768;
    for (int e = tid; e < 768; e += 256) {
        int c = e >> 8, rem = e & 255, rr = rem >> 4, cc = rem & 15;
        float v = x[((size_t)(b * 3 + c) * 224 + (hp * 16 + rr)) * 224 + wp * 16 + cc];
        short h, l; split2h(v, h, l);
        ph[base + e] = h; pl[base + e] = l;
    }
}

__global__ __launch_bounds__(256) void embed_k(
    const float* __restrict__ tpatch, const float* __restrict__ cls,
    const float* __restrict__ pos, float* __restrict__ t)
{
    int m = blockIdx.x, b = blockIdx.y, tid = threadIdx.x;
    float* dst = t + ((size_t)(b * 197 + m)) * 768;
    if (m == 0) {
        for (int e = tid; e < 768; e += 256) dst[e] = cls[e] + pos[e];
    } else {
        const float* s2 = tpatch + ((size_t)(b * 196 + m - 1)) * 768;
        for (int e = tid; e < 768; e += 256) dst[e] = s2[e] + pos[(size_t)m * 768 + e];
    }
}

// ---------------- A_hat path (layer-10 attention on RAW t, q-row 0 only) ----------------
__global__ __launch_bounds__(256) void q0_k(
    const float* __restrict__ T, const float* __restrict__ W,
    const float* __restrict__ bq, float* __restrict__ q0)
{
    int b = blockIdx.x, tid = threadIdx.x;
    __shared__ float ys[768];
    const float* yr = T + (size_t)b * 197 * 768;
    ys[tid] = yr[tid]; ys[tid + 256] = yr[tid + 256]; ys[tid + 512] = yr[tid + 512];
    __syncthreads();
    for (int d = tid; d < 768; d += 256) {
        float acc = bq[d];
        for (int k2 = 0; k2 < 768; ++k2) acc += ys[k2] * W[(size_t)k2 * 2304 + d];
        q0[(size_t)b * 768 + d] = acc;
    }
}

__global__ __launch_bounds__(256) void ahat_k(
    const float* __restrict__ kmat, const float* __restrict__ q0,
    float* __restrict__ Ahat)
{
    int b = blockIdx.x, tid = threadIdx.x;
    __shared__ float qs[64];
    __shared__ float sc[256];
    __shared__ float red[256];
    __shared__ float ah[196];
    for (int j = tid; j < 196; j += 256) ah[j] = 0.f;
    for (int h = 0; h < NHEAD; ++h) {
        __syncthreads();
        if (tid < 64) qs[tid] = q0[(size_t)b * 768 + h * 64 + tid];
        __syncthreads();
        if (tid < 197) {
            const float* kr = kmat + ((size_t)(b * 197 + tid)) * 768 + h * 64;
            float acc = 0.f;
            for (int d = 0; d < 64; ++d) acc += qs[d] * kr[d];
            sc[tid] = acc * 0.125f;
        }
        __syncthreads();
        red[tid] = (tid < 197) ? sc[tid] : -1e30f;
        __syncthreads();
        for (int off = 128; off > 0; off >>= 1) {
            if (tid < off) red[tid] = fmaxf(red[tid], red[tid + off]);
            __syncthreads();
        }
        float m = red[0];
        __syncthreads();
        float e = 0.f;
        if (tid < 197) { e = expf(sc[tid] - m); sc[tid] = e; }
        red[tid] = e;
        __syncthreads();
        for (int off = 128; off > 0; off >>= 1) {
            if (tid < off) red[tid] += red[tid + off];
            __syncthreads();
        }
        float inv = 1.f / red[0];
        if (tid >= 1 && tid < 197) ah[tid - 1] += sc[tid] * inv;
    }
    __syncthreads();
    for (int j = tid; j < 196; j += 256) Ahat[(size_t)b * 196 + j] = ah[j];
}

__global__ __launch_bounds__(256) void zo_k(
    const float* __restrict__ t, const float* __restrict__ impw,
    const float* __restrict__ impb, const float* __restrict__ Ahat,
    float* __restrict__ O)
{
    int b = blockIdx.x, tid = threadIdx.x;
    __shared__ float w[768];
    w[tid] = impw[tid]; w[tid + 256] = impw[tid + 256]; w[tid + 512] = impw[tid + 512];
    __syncthreads();
    for (int j = tid; j < 196; j += 256) {
        const float* tr = t + ((size_t)(b * 197) + 1 + j) * 768;
        float acc = impb[0];
        for (int d = 0; d < 768; ++d) acc += tr[d] * w[d];
        float z = 1.f / (1.f + expf(-acc));
        float a = Ahat[(size_t)b * 196 + j];
        O[(size_t)b * 196 + j] = a + a * z;
    }
}

// exact jax.lax.top_k semantics: descending, ties -> lower index first
__global__ __launch_bounds__(256) void topk_k(const float* __restrict__ O, int* __restrict__ idx)
{
    int b = blockIdx.x, tid = threadIdx.x;
    __shared__ float s[196];
    if (tid < 196) s[tid] = O[(size_t)b * 196 + tid];
    __syncthreads();
    if (tid < 196) {
        float v = s[tid];
        int rank = 0;
        for (int i = 0; i < 196; ++i) {
            float u = s[i];
            rank += (u > v) || (u == v && i < tid);
        }
        if (rank < 100) idx[b * 100 + rank] = tid;
    }
}

__global__ __launch_bounds__(256) void build_k(
    const float* __restrict__ t, const float* __restrict__ pos,
    const int* __restrict__ idx, float* __restrict__ inp, float* __restrict__ tp)
{
    int m = blockIdx.x, b = blockIdx.y, tid = threadIdx.x;
    float* dst = inp + ((size_t)(b * 101 + m)) * 768;
    if (m == 0) {
        const float* tr = t + (size_t)b * 197 * 768;
        for (int e = tid; e < 768; e += 256) dst[e] = tr[e] + pos[e];
    } else {
        int j = idx[b * 100 + m - 1];
        const float* tr = t + ((size_t)(b * 197) + 1 + j) * 768;
        const float* pr = pos + (size_t)(1 + j) * 768;
        float* tpr = tp + ((size_t)(b * 100) + (m - 1)) * 768;
        for (int e = tid; e < 768; e += 256) {
            float val = tr[e];
            tpr[e] = val;
            dst[e] = val + pr[e];
        }
    }
}

// ---------------- host side ----------------
extern "C" void kernel_launch(void* const* d_in, const int* in_sizes, int n_in,
                              void* d_out, int out_size, void* d_ws, size_t ws_size,
                              hipStream_t stream)
{
    const float* x      = (const float*)d_in[0];
    const float* conv_w = (const float*)d_in[1];
    const float* conv_b = (const float*)d_in[2];
    const float* cls    = (const float*)d_in[3];
    const float* pos    = (const float*)d_in[4];
    const float* ln1_s  = (const float*)d_in[5];
    const float* ln1_b  = (const float*)d_in[6];
    const float* qkv_w  = (const float*)d_in[7];
    const float* qkv_b  = (const float*)d_in[8];
    const float* proj_w = (const float*)d_in[9];
    const float* proj_b = (const float*)d_in[10];
    const float* ln2_s  = (const float*)d_in[11];
    const float* ln2_b  = (const float*)d_in[12];
    const float* mlp_w1 = (const float*)d_in[13];
    const float* mlp_b1 = (const float*)d_in[14];
    const float* mlp_w2 = (const float*)d_in[15];
    const float* mlp_b2 = (const float*)d_in[16];
    const float* fln_s  = (const float*)d_in[17];
    const float* fln_b  = (const float*)d_in[18];
    const float* imp_w  = (const float*)d_in[19];
    const float* imp_b  = (const float*)d_in[20];

    const size_t SZ_T = (size_t)32 * 197 * 768;   // 4,841,472 el
    const size_t SZ_H = (size_t)32 * 197 * 3072;  // 19,365,888 el
    const size_t SZ_W = (size_t)768 * 3072;       // 2,359,296 el

    // byte-cursor workspace layout (phase-aliased big scratch)
    char* p = (char*)d_ws;
    auto alloc = [&](size_t bytes) { char* r = p; p += (bytes + 255) & ~(size_t)255; return r; };
    float* T   = (float*)alloc(SZ_T * 4);
    float* INP = (float*)alloc((size_t)32 * 101 * 768 * 4);
    float* Q0  = (float*)alloc(24576 * 4);
    float* AH  = (float*)alloc(6272 * 4);
    float* OV  = (float*)alloc(6272 * 4);
    int*   IDX = (int*)alloc(3200 * 4);
    short* Yh  = (short*)alloc(SZ_T * 2);
    short* Yl  = (short*)alloc(SZ_T * 2);
    short* Wh  = (short*)alloc(SZ_W * 2);
    short* Wl  = (short*)alloc(SZ_W * 2);
    char*  S   = alloc((size_t)116195328);  // max(QKV 58.1MB + OB 19.4MB, H 77.5MB)
    // phase 1 (attn): QKV fp32 + OB pair
    float* QKV = (float*)S;
    short* OBh = (short*)(S + (size_t)58097664);
    short* OBl = OBh + SZ_T;
    // phase 2 (mlp): H pair overlays everything in S
    short* Hh = (short*)S;
    short* Hl = Hh + SZ_H;

    float* out0 = (float*)d_out;                        // (32,101,768)
    float* out1 = out0 + (size_t)32 * 101 * 768;        // top_patches (32,100,768)

    auto cvt = [&](const float* W, int K, int N, int ld) {
        ts_k<<<dim3(N / 32, K / 32), 256, 0, stream>>>(W, ld, Wh, Wl, K, N);
    };

    // ---- patch embed ----
    esplit_k<<<(768 * 768) / 256, 256, 0, stream>>>(conv_w, Wh, Wl, 768 * 768); // conv_w already [n][k]
    gather_k<<<dim3(196, 32), 256, 0, stream>>>(x, Yh, Yl);
    mgemm_k<0><<<dim3(6, 49), 256, 0, stream>>>(Yh, Yl, Wh, Wl, conv_b, nullptr,
                                                QKV, nullptr, nullptr, 6272, 768, 768, 768);
    embed_k<<<dim3(197, 32), 256, 0, stream>>>(QKV, cls, pos, T);

    auto run_block = [&](float* X, int L, int i) {
        int M = 32 * L;
        int mt = (M + 127) / 128;
        ln_k<1><<<M, 256, 0, stream>>>(X, ln1_s + i * 768, ln1_b + i * 768, nullptr, Yh, Yl);
        cvt(qkv_w + (size_t)i * 768 * 2304, 768, 2304, 2304);
        mgemm_k<0><<<dim3(18, mt), 256, 0, stream>>>(Yh, Yl, Wh, Wl, qkv_b + (size_t)i * 2304,
                                                     nullptr, QKV, nullptr, nullptr, M, 2304, 768, 2304);
        attn2_k<<<dim3(NHEAD, 32), 256, 0, stream>>>(QKV, OBh, OBl, L);
        cvt(proj_w + (size_t)i * 768 * 768, 768, 768, 768);
        mgemm_k<1><<<dim3(6, mt), 256, 0, stream>>>(OBh, OBl, Wh, Wl, proj_b + (size_t)i * 768,
                                                    X, X, nullptr, nullptr, M, 768, 768, 768);
        ln_k<1><<<M, 256, 0, stream>>>(X, ln2_s + i * 768, ln2_b + i * 768, nullptr, Yh, Yl);
        cvt(mlp_w1 + (size_t)i * 768 * 3072, 768, 3072, 3072);
        mgemm_k<2><<<dim3(24, mt), 256, 0, stream>>>(Yh, Yl, Wh, Wl, mlp_b1 + (size_t)i * 3072,
                                                     nullptr, nullptr, Hh, Hl, M, 3072, 768, 3072);
        cvt(mlp_w2 + (size_t)i * 3072 * 768, 3072, 768, 768);
        mgemm_k<1><<<dim3(6, mt), 256, 0, stream>>>(Hh, Hl, Wh, Wl, mlp_b2 + (size_t)i * 768,
                                                    X, X, nullptr, nullptr, M, 768, 3072, 768);
    };

    for (int i = 0; i < 11; ++i) run_block(T, 197, i);

    // ---- A_hat: layer-10 attention weights on RAW t (no LN), q-row 0 only ----
    esplit_k<<<(int)(SZ_T / 256), 256, 0, stream>>>(T, Yh, Yl, (int)SZ_T);
    cvt(qkv_w + (size_t)10 * 768 * 2304 + 768, 768, 768, 2304);     // K-slice of qkv_w[10]
    mgemm_k<0><<<dim3(6, 50), 256, 0, stream>>>(Yh, Yl, Wh, Wl, qkv_b + (size_t)10 * 2304 + 768,
                                                nullptr, QKV, nullptr, nullptr, 6304, 768, 768, 768);
    q0_k<<<32, 256, 0, stream>>>(T, qkv_w + (size_t)10 * 768 * 2304, qkv_b + (size_t)10 * 2304, Q0);
    ahat_k<<<32, 256, 0, stream>>>(QKV, Q0, AH);
    zo_k<<<32, 256, 0, stream>>>(T, imp_w, imp_b, AH, OV);
    topk_k<<<32, 256, 0, stream>>>(OV, IDX);
    build_k<<<dim3(101, 32), 256, 0, stream>>>(T, pos, IDX, INP, out1);

    // ---- last block on gathered tokens (L=101, layer 11) ----
    run_block(INP, 101, 11);

    // ---- final LN -> out0 ----
    ln_k<0><<<32 * 101, 256, 0, stream>>>(INP, fln_s, fln_b, out0, nullptr, nullptr);

    (void)in_sizes; (void)n_in; (void)out_size; (void)ws_size;
}

// Round 3
// 7740.549 us; speedup vs baseline: 2.4248x; 1.0760x over previous
//
#include <hip/hip_runtime.h>
#include <hip/hip_fp16.h>
#include <cmath>

// ViT backbone. GEMMs via fp16x3 (pair-split) error-compensated MFMA (16x16x32_f16):
// x = h + l (both fp16, RN), products l*H + h*L + h*H accumulated fp32.
// Per-product error ~2^-21 |x||y|; fp16 products exact in fp32 accum.
// Rest fp32. D=768, H=12, DH=64, NL=12, B=32, L=197 (main) / 101 (last block), k=100.
//
// R1: attention one block per (b,h), K/V LDS-resident, register-tiled.
// R2: bf16x6 -> fp16x3 + double-buffered 2-phase mgemm.
// R3: attention v3 - K stored NATURAL (padded [k2][68]) with strided-k2 lane
//     ownership: kills the 8-way transposed-read + 16-way transpose-write bank
//     conflicts (7.8M cycles/dispatch). q-tiles split across grid.z=2 (768
//     blocks -> 3 full CU rounds instead of 1.5). CMAX templated so register
//     arrays stay statically indexed; L=101 does 4/7 of the score work.

#define NHEAD 12

typedef __attribute__((ext_vector_type(8))) _Float16 half8;
typedef __attribute__((ext_vector_type(4))) float f32x4;

// ---- RN fp16 pair split: x = h + l, dropped error ~2^-22 |x| ----
__device__ __forceinline__ void split2h(float x, short& h, short& l) {
    __half hh = __float2half(x);            // RN
    float r = x - __half2float(hh);         // exact in fp32
    h = __half_as_short(hh);
    l = __half_as_short(__float2half(r));   // RN of residual
}

__device__ __forceinline__ void ldg2lds(const void* g, void* l) {
    __builtin_amdgcn_global_load_lds((const __attribute__((address_space(1))) void*)g,
                                     (__attribute__((address_space(3))) void*)l, 16, 0, 0);
}

// ---------------- MFMA GEMM: C(MxN) = A(MxK) @ Bt(NxK)^T + bias [+R] [gelu] ----------------
// A as fp16 pair (Ah,Al) row-major [M][K]; B as fp16 pair [N][K] (pre-transposed).
// OP 0: C = acc + bias                 (fp32 out)
// OP 1: C = acc + bias + R             (fp32 out, residual)
// OP 2: C* = split2(gelu(acc+bias))    (fp16-pair out)
template<int OP>
__global__ __launch_bounds__(256, 2) void mgemm_k(
    const short* __restrict__ Ah, const short* __restrict__ Al,
    const short* __restrict__ Bh, const short* __restrict__ Bl,
    const float* __restrict__ bias, const float* __restrict__ R,
    float* __restrict__ C, short* __restrict__ Ch, short* __restrict__ Cl,
    int M, int N, int K, int ldc)
{
    __shared__ short sA[2][2][128 * 32];   // [dbuf][h/l][row][k]  32 KB
    __shared__ short sB[2][2][128 * 32];   //                      32 KB
    const int tid = threadIdx.x;
    const int wid = tid >> 6, lane = tid & 63;
    const int wm = wid >> 1, wn = wid & 1;
    const int quad = lane >> 4, l15 = lane & 15;
    const int row0 = blockIdx.y * 128, col0 = blockIdx.x * 128;

    f32x4 acc[4][4];
#pragma unroll
    for (int i = 0; i < 4; ++i)
#pragma unroll
        for (int j = 0; j < 4; ++j) { acc[i][j][0] = 0.f; acc[i][j][1] = 0.f; acc[i][j][2] = 0.f; acc[i][j][3] = 0.f; }

    const int srow = lane >> 2;          // 0..15
    const int schunk = (lane & 3) * 8;   // k-element offset of this lane's 16B
    const int KT = K >> 5;

    auto stage = [&](int buf, int kt) {
        int kk = kt << 5;
#pragma unroll
        for (int rnd = 0; rnd < 2; ++rnd) {
            int m = rnd * 64 + wid * 16 + srow;            // row within tile, 0..127
            int gr = row0 + m; if (gr > M - 1) gr = M - 1; // clamp (stores masked later)
            int gn = col0 + m;                             // N always multiple of 128
            size_t ao = (size_t)gr * K + kk + schunk;
            size_t bo = (size_t)gn * K + kk + schunk;
            int lofs = (rnd * 64 + wid * 16) * 32;         // wave-uniform LDS base
            ldg2lds(Ah + ao, &sA[buf][0][lofs]);
            ldg2lds(Al + ao, &sA[buf][1][lofs]);
            ldg2lds(Bh + bo, &sB[buf][0][lofs]);
            ldg2lds(Bl + bo, &sB[buf][1][lofs]);
        }
    };

    stage(0, 0);
    for (int kt = 0; kt < KT; ++kt) {
        int cur = kt & 1;
        __syncthreads();                    // drains prefetch (covered by prev compute)
        if (kt + 1 < KT) stage(cur ^ 1, kt + 1);

        half8 a[4][2];
#pragma unroll
        for (int i = 0; i < 4; ++i) {
            int m = wm * 64 + i * 16 + l15;
#pragma unroll
            for (int p = 0; p < 2; ++p)
                a[i][p] = *(const half8*)&sA[cur][p][m * 32 + quad * 8];
        }
#pragma unroll
        for (int j = 0; j < 4; ++j) {
            int n = wn * 64 + j * 16 + l15;
            half8 bh = *(const half8*)&sB[cur][0][n * 32 + quad * 8];
            half8 bl = *(const half8*)&sB[cur][1][n * 32 + quad * 8];
#pragma unroll
            for (int i = 0; i < 4; ++i) {
                // small terms first, then large (chained fp32 accumulate)
                acc[i][j] = __builtin_amdgcn_mfma_f32_16x16x32_f16(a[i][1], bh, acc[i][j], 0, 0, 0); // l*H
                acc[i][j] = __builtin_amdgcn_mfma_f32_16x16x32_f16(a[i][0], bl, acc[i][j], 0, 0, 0); // h*L
                acc[i][j] = __builtin_amdgcn_mfma_f32_16x16x32_f16(a[i][0], bh, acc[i][j], 0, 0, 0); // h*H
            }
        }
    }

#pragma unroll
    for (int i = 0; i < 4; ++i) {
#pragma unroll
        for (int r = 0; r < 4; ++r) {
            int gr = row0 + wm * 64 + i * 16 + quad * 4 + r;
            if (gr >= M) continue;
#pragma unroll
            for (int j = 0; j < 4; ++j) {
                int gc = col0 + wn * 64 + j * 16 + l15;
                float v = acc[i][j][r] + bias[gc];
                if (OP == 1) v += R[(size_t)gr * ldc + gc];
                if (OP == 2) {
                    v = 0.5f * v * (1.f + erff(v * 0.70710678118654752f));
                    short h, l; split2h(v, h, l);
                    size_t o = (size_t)gr * ldc + gc;
                    Ch[o] = h; Cl[o] = l;
                } else {
                    C[(size_t)gr * ldc + gc] = v;
                }
            }
        }
    }
}

// ---------------- weight transpose + split: W[K][N] (ld) -> pair [N][K] ----------------
__global__ __launch_bounds__(256) void ts_k(
    const float* __restrict__ W, int ld,
    short* __restrict__ Bh, short* __restrict__ Bl, int K, int N)
{
    __shared__ float tile[32][33];
    int n0 = blockIdx.x * 32, k0 = blockIdx.y * 32;
    int c = threadIdx.x & 31, r0 = threadIdx.x >> 5;
    for (int rr = r0; rr < 32; rr += 8)
        tile[rr][c] = W[(size_t)(k0 + rr) * ld + n0 + c];
    __syncthreads();
    for (int rr = r0; rr < 32; rr += 8) {
        float v = tile[c][rr];  // = W[k0+c][n0+rr]
        short h, l; split2h(v, h, l);
        size_t o = (size_t)(n0 + rr) * K + k0 + c;
        Bh[o] = h; Bl[o] = l;
    }
}

// ---------------- elementwise split (conv_w already [n][k]; also T -> pair) ----------------
__global__ __launch_bounds__(256) void esplit_k(
    const float* __restrict__ X, short* __restrict__ H,
    short* __restrict__ Lo, int n)
{
    int i = blockIdx.x * 256 + threadIdx.x;
    if (i < n) { short h, l; split2h(X[i], h, l); H[i] = h; Lo[i] = l; }
}

// ---------------- LayerNorm row=768; MODE0: fp32 out, MODE1: fp16-pair out ----------------
template<int MODE>
__global__ __launch_bounds__(256) void ln_k(
    const float* __restrict__ x, const float* __restrict__ s,
    const float* __restrict__ bb, float* __restrict__ y,
    short* __restrict__ yh, short* __restrict__ yl)
{
    int r = blockIdx.x;
    int tid = threadIdx.x;
    const float* xr = x + (size_t)r * 768;
    float v0 = xr[tid], v1 = xr[tid + 256], v2 = xr[tid + 512];
    __shared__ float red[256];
    red[tid] = v0 + v1 + v2;
    __syncthreads();
    for (int off = 128; off > 0; off >>= 1) {
        if (tid < off) red[tid] += red[tid + off];
        __syncthreads();
    }
    float m = red[0] / 768.f;
    __syncthreads();
    float d0 = v0 - m, d1 = v1 - m, d2 = v2 - m;
    red[tid] = d0 * d0 + d1 * d1 + d2 * d2;
    __syncthreads();
    for (int off = 128; off > 0; off >>= 1) {
        if (tid < off) red[tid] += red[tid + off];
        __syncthreads();
    }
    float inv = 1.f / sqrtf(red[0] / 768.f + 1e-6f);
    float o0 = d0 * inv * s[tid] + bb[tid];
    float o1 = d1 * inv * s[tid + 256] + bb[tid + 256];
    float o2 = d2 * inv * s[tid + 512] + bb[tid + 512];
    if (MODE == 0) {
        float* yr = y + (size_t)r * 768;
        yr[tid] = o0; yr[tid + 256] = o1; yr[tid + 512] = o2;
    } else {
        size_t base = (size_t)r * 768;
        short h, l;
        split2h(o0, h, l); yh[base + tid] = h;       yl[base + tid] = l;
        split2h(o1, h, l); yh[base + tid + 256] = h; yl[base + tid + 256] = l;
        split2h(o2, h, l); yh[base + tid + 512] = h; yl[base + tid + 512] = l;
    }
}

// ---------------- fused attention v3: one block per (b,h,zhalf) ----------------
// K natural in LDS sK[k2][68] (pad 68 -> 16B aligned, 4-way worst on reads,
// 2-way free on staging writes). Lane owns STRIDED k2 = ko + 32c so score
// reads rotate across bank groups. V natural sV[k2][64] via global_load_lds.
// ps straight [k2][36]: score-write 4-way, softmax scalar conflict-free,
// PV float4 broadcast reads. Pad k2 rows get -1e30 -> exp()=0.
// grid.z=2 splits q-tiles (even/odd) across blocks for CU-round packing.
// CMAX = ceil(L/32) templated: static register indexing, less work at L=101.
template<int CMAX>
__global__ __launch_bounds__(256) void attn3_k(
    const float* __restrict__ qkv,
    short* __restrict__ oh, short* __restrict__ ol, int L)
{
    __shared__ __align__(16) float sK[224 * 68];   // [k2][d] pad 68  60.9 KB
    __shared__ __align__(16) float sV[208 * 64];   // [k2][d]         53.2 KB
    __shared__ __align__(16) float qs[32 * 64];    // [q][d]           8 KB
    __shared__ __align__(16) float ps[224 * 36];   // [k2][q] pad 36  32.3 KB
    __shared__ float red[8 * 32];
    __shared__ float sinv[32];

    const int tid = threadIdx.x;
    const int h = blockIdx.x, b = blockIdx.y, z = blockIdx.z;
    const float* base = qkv + (size_t)b * L * 2304;
    const float* qbase = base + h * 64;
    const float* kbase = base + 768 + h * 64;
    const float* vbase = base + 1536 + h * 64;

    // ---- stage K natural, padded rows (write banks (4r+c)%32: 2-way, free) ----
    for (int idx = tid; idx < L * 16; idx += 256) {
        int r = idx >> 4, c = (idx & 15) << 2;
        *(float4*)&sK[r * 68 + c] = *(const float4*)(kbase + (size_t)r * 2304 + c);
    }
    // ---- stage V natural via global_load_lds (row-clamped, dest linear) ----
    {
        int vIters = (L * 16 + 255) >> 8;
        for (int p2 = 0; p2 < vIters; ++p2) {
            int idx = p2 * 256 + tid;
            int r = idx >> 4; if (r > L - 1) r = L - 1;
            ldg2lds(vbase + (size_t)r * 2304 + ((idx & 15) << 2), &sV[idx * 4]);
        }
    }

    const int ko = tid & 31, qq8 = tid >> 5;   // scores: k2 lane (strided), q-quad
    const int qsm = tid & 31, seg = tid >> 5;  // softmax: q col, k2 segment
    const int pq = tid & 7, dd = tid >> 3;     // PV: q-quad, d-pair
    const int ntiles = (L + 31) >> 5;
    const int Lr4 = (L + 3) & ~3;
    const int rps = CMAX * 4;                  // softmax rows per segment (K2R/8)

    for (int t = z; t < ntiles; t += 2) {
        int q0 = t << 5;
        __syncthreads();   // staging done / prev tile's PV done with ps+qs
        {
            int idx = tid;
            int r = q0 + (idx >> 4); if (r > L - 1) r = L - 1;
            ldg2lds(qbase + (size_t)r * 2304 + ((idx & 15) << 2), &qs[idx * 4]);
            idx = 256 + tid;
            r = q0 + (idx >> 4); if (r > L - 1) r = L - 1;
            ldg2lds(qbase + (size_t)r * 2304 + ((idx & 15) << 2), &qs[idx * 4]);
        }
        __syncthreads();   // qs ready (barrier drains vmcnt)

        // ---- scores: acc[c][q] over d=64; lane's k2 = ko + 32c ----
        float acc[CMAX][4];
#pragma unroll
        for (int c = 0; c < CMAX; ++c)
#pragma unroll
            for (int j = 0; j < 4; ++j) acc[c][j] = 0.f;

#pragma unroll 4
        for (int d4 = 0; d4 < 16; ++d4) {
            float4 kv[CMAX];
#pragma unroll
            for (int c = 0; c < CMAX; ++c)
                kv[c] = *(const float4*)&sK[(ko + 32 * c) * 68 + d4 * 4];
#pragma unroll
            for (int j = 0; j < 4; ++j) {
                float4 qv = *(const float4*)&qs[(qq8 * 4 + j) * 64 + d4 * 4];
#pragma unroll
                for (int c = 0; c < CMAX; ++c) {
                    acc[c][j] = fmaf(qv.x, kv[c].x, acc[c][j]);
                    acc[c][j] = fmaf(qv.y, kv[c].y, acc[c][j]);
                    acc[c][j] = fmaf(qv.z, kv[c].z, acc[c][j]);
                    acc[c][j] = fmaf(qv.w, kv[c].w, acc[c][j]);
                }
            }
        }
        // write ps [k2][q]; scale 1/8; mask pad k2 rows with -1e30
#pragma unroll
        for (int c = 0; c < CMAX; ++c) {
            int k2 = ko + 32 * c;
            float4 w;
            if (k2 < L) {
                w.x = acc[c][0] * 0.125f; w.y = acc[c][1] * 0.125f;
                w.z = acc[c][2] * 0.125f; w.w = acc[c][3] * 0.125f;
            } else { w.x = -1e30f; w.y = -1e30f; w.z = -1e30f; w.w = -1e30f; }
            *(float4*)&ps[k2 * 36 + qq8 * 4] = w;
        }
        __syncthreads();

        // ---- softmax over k2 per q column (scalar reads conflict-free) ----
        float mloc = -1e30f;
#pragma unroll 4
        for (int j2 = 0; j2 < rps; ++j2)
            mloc = fmaxf(mloc, ps[(seg * rps + j2) * 36 + qsm]);
        red[seg * 32 + qsm] = mloc;
        __syncthreads();
        float mm = red[qsm];
#pragma unroll
        for (int s2 = 1; s2 < 8; ++s2) mm = fmaxf(mm, red[s2 * 32 + qsm]);
        __syncthreads();   // all max-reads done before red reuse
        float sum = 0.f;
#pragma unroll 4
        for (int j2 = 0; j2 < rps; ++j2) {
            int o2 = (seg * rps + j2) * 36 + qsm;
            float e = expf(ps[o2] - mm);
            ps[o2] = e;
            sum += e;
        }
        red[seg * 32 + qsm] = sum;
        __syncthreads();
        float tot = red[qsm];
#pragma unroll
        for (int s2 = 1; s2 < 8; ++s2) tot += red[s2 * 32 + qsm];
        if (tid < 32) sinv[tid] = 1.f / tot;
        __syncthreads();

        // ---- PV: pacc[4 q][2 d]; ps reads broadcast, sV reads 2-way free ----
        float pacc[4][2];
#pragma unroll
        for (int j = 0; j < 4; ++j) { pacc[j][0] = 0.f; pacc[j][1] = 0.f; }
        for (int k2 = 0; k2 < Lr4; k2 += 4) {
#pragma unroll
            for (int i2 = 0; i2 < 4; ++i2) {
                int kk = k2 + i2;
                const float4 pv = *(const float4*)&ps[kk * 36 + pq * 4];
                const float2 vv = *(const float2*)&sV[kk * 64 + dd * 2];
                pacc[0][0] = fmaf(pv.x, vv.x, pacc[0][0]);
                pacc[0][1] = fmaf(pv.x, vv.y, pacc[0][1]);
                pacc[1][0] = fmaf(pv.y, vv.x, pacc[1][0]);
                pacc[1][1] = fmaf(pv.y, vv.y, pacc[1][1]);
                pacc[2][0] = fmaf(pv.z, vv.x, pacc[2][0]);
                pacc[2][1] = fmaf(pv.z, vv.y, pacc[2][1]);
                pacc[3][0] = fmaf(pv.w, vv.x, pacc[3][0]);
                pacc[3][1] = fmaf(pv.w, vv.y, pacc[3][1]);
            }
        }
#pragma unroll
        for (int j = 0; j < 4; ++j) {
            int grow = q0 + pq * 4 + j;
            if (grow >= L) continue;
            float inv = sinv[pq * 4 + j];
            size_t o = ((size_t)(b * L + grow)) * 768 + h * 64 + dd * 2;
            short hh, ll;
            split2h(pacc[j][0] * inv, hh, ll);
            oh[o] = hh; ol[o] = ll;
            split2h(pacc[j][1] * inv, hh, ll);
            oh[o + 1] = hh; ol[o + 1] = ll;
        }
    }
}

// ---------------- patch embed helpers ----------------
__global__ __launch_bounds__(256) void gather_k(
    const float* __restrict__ x,
    short* __restrict__ ph, short* __restrict__ pl)
{
    int n = blockIdx.x, b = blockIdx.y, tid = threadIdx.x;
    int hp = n / 14, wp = n % 14;
    size_t base = ((size_t)(b * 196 + n)) * 768;
    for (int e = tid; e < 768; e += 256) {
        int c = e >> 8, rem = e & 255, rr = rem >> 4, cc = rem & 15;
        float v = x[((size_t)(b * 3 + c) * 224 + (hp * 16 + rr)) * 224 + wp * 16 + cc];
        short h, l; split2h(v, h, l);
        ph[base + e] = h; pl[base + e] = l;
    }
}

__global__ __launch_bounds__(256) void embed_k(
    const float* __restrict__ tpatch, const float* __restrict__ cls,
    const float* __restrict__ pos, float* __restrict__ t)
{
    int m = blockIdx.x, b = blockIdx.y, tid = threadIdx.x;
    float* dst = t + ((size_t)(b * 197 + m)) * 768;
    if (m == 0) {
        for (int e = tid; e < 768; e += 256) dst[e] = cls[e] + pos[e];
    } else {
        const float* s2 = tpatch + ((size_t)(b * 196 + m - 1)) * 768;
        for (int e = tid; e < 768; e += 256) dst[e] = s2[e] + pos[(size_t)m * 768 + e];
    }
}

// ---------------- A_hat path (layer-10 attention on RAW t, q-row 0 only) ----------------
__global__ __launch_bounds__(256) void q0_k(
    const float* __restrict__ T, const float* __restrict__ W,
    const float* __restrict__ bq, float* __restrict__ q0)
{
    int b = blockIdx.x, tid = threadIdx.x;
    __shared__ float ys[768];
    const float* yr = T + (size_t)b * 197 * 768;
    ys[tid] = yr[tid]; ys[tid + 256] = yr[tid + 256]; ys[tid + 512] = yr[tid + 512];
    __syncthreads();
    for (int d = tid; d < 768; d += 256) {
        float acc = bq[d];
        for (int k2 = 0; k2 < 768; ++k2) acc += ys[k2] * W[(size_t)k2 * 2304 + d];
        q0[(size_t)b * 768 + d] = acc;
    }
}

__global__ __launch_bounds__(256) void ahat_k(
    const float* __restrict__ kmat, const float* __restrict__ q0,
    float* __restrict__ Ahat)
{
    int b = blockIdx.x, tid = threadIdx.x;
    __shared__ float qs[64];
    __shared__ float sc[256];
    __shared__ float red[256];
    __shared__ float ah[196];
    for (int j = tid; j < 196; j += 256) ah[j] = 0.f;
    for (int h = 0; h < NHEAD; ++h) {
        __syncthreads();
        if (tid < 64) qs[tid] = q0[(size_t)b * 768 + h * 64 + tid];
        __syncthreads();
        if (tid < 197) {
            const float* kr = kmat + ((size_t)(b * 197 + tid)) * 768 + h * 64;
            float acc = 0.f;
            for (int d = 0; d < 64; ++d) acc += qs[d] * kr[d];
            sc[tid] = acc * 0.125f;
        }
        __syncthreads();
        red[tid] = (tid < 197) ? sc[tid] : -1e30f;
        __syncthreads();
        for (int off = 128; off > 0; off >>= 1) {
            if (tid < off) red[tid] = fmaxf(red[tid], red[tid + off]);
            __syncthreads();
        }
        float m = red[0];
        __syncthreads();
        float e = 0.f;
        if (tid < 197) { e = expf(sc[tid] - m); sc[tid] = e; }
        red[tid] = e;
        __syncthreads();
        for (int off = 128; off > 0; off >>= 1) {
            if (tid < off) red[tid] += red[tid + off];
            __syncthreads();
        }
        float inv = 1.f / red[0];
        if (tid >= 1 && tid < 197) ah[tid - 1] += sc[tid] * inv;
    }
    __syncthreads();
    for (int j = tid; j < 196; j += 256) Ahat[(size_t)b * 196 + j] = ah[j];
}

__global__ __launch_bounds__(256) void zo_k(
    const float* __restrict__ t, const float* __restrict__ impw,
    const float* __restrict__ impb, const float* __restrict__ Ahat,
    float* __restrict__ O)
{
    int b = blockIdx.x, tid = threadIdx.x;
    __shared__ float w[768];
    w[tid] = impw[tid]; w[tid + 256] = impw[tid + 256]; w[tid + 512] = impw[tid + 512];
    __syncthreads();
    for (int j = tid; j < 196; j += 256) {
        const float* tr = t + ((size_t)(b * 197) + 1 + j) * 768;
        float acc = impb[0];
        for (int d = 0; d < 768; ++d) acc += tr[d] * w[d];
        float z = 1.f / (1.f + expf(-acc));
        float a = Ahat[(size_t)b * 196 + j];
        O[(size_t)b * 196 + j] = a + a * z;
    }
}

// exact jax.lax.top_k semantics: descending, ties -> lower index first
__global__ __launch_bounds__(256) void topk_k(const float* __restrict__ O, int* __restrict__ idx)
{
    int b = blockIdx.x, tid = threadIdx.x;
    __shared__ float s[196];
    if (tid < 196) s[tid] = O[(size_t)b * 196 + tid];
    __syncthreads();
    if (tid < 196) {
        float v = s[tid];
        int rank = 0;
        for (int i = 0; i < 196; ++i) {
            float u = s[i];
            rank += (u > v) || (u == v && i < tid);
        }
        if (rank < 100) idx[b * 100 + rank] = tid;
    }
}

__global__ __launch_bounds__(256) void build_k(
    const float* __restrict__ t, const float* __restrict__ pos,
    const int* __restrict__ idx, float* __restrict__ inp, float* __restrict__ tp)
{
    int m = blockIdx.x, b = blockIdx.y, tid = threadIdx.x;
    float* dst = inp + ((size_t)(b * 101 + m)) * 768;
    if (m == 0) {
        const float* tr = t + (size_t)b * 197 * 768;
        for (int e = tid; e < 768; e += 256) dst[e] = tr[e] + pos[e];
    } else {
        int j = idx[b * 100 + m - 1];
        const float* tr = t + ((size_t)(b * 197) + 1 + j) * 768;
        const float* pr = pos + (size_t)(1 + j) * 768;
        float* tpr = tp + ((size_t)(b * 100) + (m - 1)) * 768;
        for (int e = tid; e < 768; e += 256) {
            float val = tr[e];
            tpr[e] = val;
            dst[e] = val + pr[e];
        }
    }
}

// ---------------- host side ----------------
extern "C" void kernel_launch(void* const* d_in, const int* in_sizes, int n_in,
                              void* d_out, int out_size, void* d_ws, size_t ws_size,
                              hipStream_t stream)
{
    const float* x      = (const float*)d_in[0];
    const float* conv_w = (const float*)d_in[1];
    const float* conv_b = (const float*)d_in[2];
    const float* cls    = (const float*)d_in[3];
    const float* pos    = (const float*)d_in[4];
    const float* ln1_s  = (const float*)d_in[5];
    const float* ln1_b  = (const float*)d_in[6];
    const float* qkv_w  = (const float*)d_in[7];
    const float* qkv_b  = (const float*)d_in[8];
    const float* proj_w = (const float*)d_in[9];
    const float* proj_b = (const float*)d_in[10];
    const float* ln2_s  = (const float*)d_in[11];
    const float* ln2_b  = (const float*)d_in[12];
    const float* mlp_w1 = (const float*)d_in[13];
    const float* mlp_b1 = (const float*)d_in[14];
    const float* mlp_w2 = (const float*)d_in[15];
    const float* mlp_b2 = (const float*)d_in[16];
    const float* fln_s  = (const float*)d_in[17];
    const float* fln_b  = (const float*)d_in[18];
    const float* imp_w  = (const float*)d_in[19];
    const float* imp_b  = (const float*)d_in[20];

    const size_t SZ_T = (size_t)32 * 197 * 768;   // 4,841,472 el
    const size_t SZ_H = (size_t)32 * 197 * 3072;  // 19,365,888 el
    const size_t SZ_W = (size_t)768 * 3072;       // 2,359,296 el

    // byte-cursor workspace layout (phase-aliased big scratch)
    char* p = (char*)d_ws;
    auto alloc = [&](size_t bytes) { char* r = p; p += (bytes + 255) & ~(size_t)255; return r; };
    float* T   = (float*)alloc(SZ_T * 4);
    float* INP = (float*)alloc((size_t)32 * 101 * 768 * 4);
    float* Q0  = (float*)alloc(24576 * 4);
    float* AH  = (float*)alloc(6272 * 4);
    float* OV  = (float*)alloc(6272 * 4);
    int*   IDX = (int*)alloc(3200 * 4);
    short* Yh  = (short*)alloc(SZ_T * 2);
    short* Yl  = (short*)alloc(SZ_T * 2);
    short* Wh  = (short*)alloc(SZ_W * 2);
    short* Wl  = (short*)alloc(SZ_W * 2);
    char*  S   = alloc((size_t)116195328);  // max(QKV 58.1MB + OB 19.4MB, H 77.5MB)
    // phase 1 (attn): QKV fp32 + OB pair
    float* QKV = (float*)S;
    short* OBh = (short*)(S + (size_t)58097664);
    short* OBl = OBh + SZ_T;
    // phase 2 (mlp): H pair overlays everything in S
    short* Hh = (short*)S;
    short* Hl = Hh + SZ_H;

    float* out0 = (float*)d_out;                        // (32,101,768)
    float* out1 = out0 + (size_t)32 * 101 * 768;        // top_patches (32,100,768)

    auto cvt = [&](const float* W, int K, int N, int ld) {
        ts_k<<<dim3(N / 32, K / 32), 256, 0, stream>>>(W, ld, Wh, Wl, K, N);
    };

    // ---- patch embed ----
    esplit_k<<<(768 * 768) / 256, 256, 0, stream>>>(conv_w, Wh, Wl, 768 * 768); // conv_w already [n][k]
    gather_k<<<dim3(196, 32), 256, 0, stream>>>(x, Yh, Yl);
    mgemm_k<0><<<dim3(6, 49), 256, 0, stream>>>(Yh, Yl, Wh, Wl, conv_b, nullptr,
                                                QKV, nullptr, nullptr, 6272, 768, 768, 768);
    embed_k<<<dim3(197, 32), 256, 0, stream>>>(QKV, cls, pos, T);

    auto run_block = [&](float* X, int L, int i) {
        int M = 32 * L;
        int mt = (M + 127) / 128;
        ln_k<1><<<M, 256, 0, stream>>>(X, ln1_s + i * 768, ln1_b + i * 768, nullptr, Yh, Yl);
        cvt(qkv_w + (size_t)i * 768 * 2304, 768, 2304, 2304);
        mgemm_k<0><<<dim3(18, mt), 256, 0, stream>>>(Yh, Yl, Wh, Wl, qkv_b + (size_t)i * 2304,
                                                     nullptr, QKV, nullptr, nullptr, M, 2304, 768, 2304);
        if (L == 197)
            attn3_k<7><<<dim3(NHEAD, 32, 2), 256, 0, stream>>>(QKV, OBh, OBl, L);
        else
            attn3_k<4><<<dim3(NHEAD, 32, 2), 256, 0, stream>>>(QKV, OBh, OBl, L);
        cvt(proj_w + (size_t)i * 768 * 768, 768, 768, 768);
        mgemm_k<1><<<dim3(6, mt), 256, 0, stream>>>(OBh, OBl, Wh, Wl, proj_b + (size_t)i * 768,
                                                    X, X, nullptr, nullptr, M, 768, 768, 768);
        ln_k<1><<<M, 256, 0, stream>>>(X, ln2_s + i * 768, ln2_b + i * 768, nullptr, Yh, Yl);
        cvt(mlp_w1 + (size_t)i * 768 * 3072, 768, 3072, 3072);
        mgemm_k<2><<<dim3(24, mt), 256, 0, stream>>>(Yh, Yl, Wh, Wl, mlp_b1 + (size_t)i * 3072,
                                                     nullptr, nullptr, Hh, Hl, M, 3072, 768, 3072);
        cvt(mlp_w2 + (size_t)i * 3072 * 768, 3072, 768, 768);
        mgemm_k<1><<<dim3(6, mt), 256, 0, stream>>>(Hh, Hl, Wh, Wl, mlp_b2 + (size_t)i * 768,
                                                    X, X, nullptr, nullptr, M, 768, 3072, 768);
    };

    for (int i = 0; i < 11; ++i) run_block(T, 197, i);

    // ---- A_hat: layer-10 attention weights on RAW t (no LN), q-row 0 only ----
    esplit_k<<<(int)(SZ_T / 256), 256, 0, stream>>>(T, Yh, Yl, (int)SZ_T);
    cvt(qkv_w + (size_t)10 * 768 * 2304 + 768, 768, 768, 2304);     // K-slice of qkv_w[10]
    mgemm_k<0><<<dim3(6, 50), 256, 0, stream>>>(Yh, Yl, Wh, Wl, qkv_b + (size_t)10 * 2304 + 768,
                                                nullptr, QKV, nullptr, nullptr, 6304, 768, 768, 768);
    q0_k<<<32, 256, 0, stream>>>(T, qkv_w + (size_t)10 * 768 * 2304, qkv_b + (size_t)10 * 2304, Q0);
    ahat_k<<<32, 256, 0, stream>>>(QKV, Q0, AH);
    zo_k<<<32, 256, 0, stream>>>(T, imp_w, imp_b, AH, OV);
    topk_k<<<32, 256, 0, stream>>>(OV, IDX);
    build_k<<<dim3(101, 32), 256, 0, stream>>>(T, pos, IDX, INP, out1);

    // ---- last block on gathered tokens (L=101, layer 11) ----
    run_block(INP, 101, 11);

    // ---- final LN -> out0 ----
    ln_k<0><<<32 * 101, 256, 0, stream>>>(INP, fln_s, fln_b, out0, nullptr, nullptr);

    (void)in_sizes; (void)n_in; (void)out_size; (void)ws_size;
}